// Round 1
// baseline (417.585 us; speedup 1.0000x reference)
//
#include <hip/hip_runtime.h>

#define Bsz 128
#define Tsz 256
#define Nsz 128
#define Asz 512
#define Vsz 512

__device__ __forceinline__ float fast_tanh(float x) {
  float ax = fabsf(x);
  float e = __expf(-2.f * ax);
  float t = (1.f - e) / (1.f + e);
  return copysignf(t, x);
}

// one wave per row: dot(row, w) -> dst[row]
__global__ __launch_bounds__(256) void lin_kernel(
    const float* __restrict__ AO, const float* __restrict__ inputs,
    const float* __restrict__ a_w, const float* __restrict__ b_w,
    float* __restrict__ lin_a, float* __restrict__ lin_b)
{
  int gw = (blockIdx.x * 256 + threadIdx.x) >> 6;
  int lane = threadIdx.x & 63;
  const float* src; const float* w; float* dst;
  if (gw < Bsz * Nsz) {
    src = AO + (long)gw * Asz; w = a_w; dst = lin_a + gw;
  } else {
    int r = gw - Bsz * Nsz;
    src = inputs + (long)r * Vsz; w = b_w; dst = lin_b + r;
  }
  float4 x0 = *(const float4*)(src + lane * 4);
  float4 x1 = *(const float4*)(src + 256 + lane * 4);
  float4 w0 = *(const float4*)(w + lane * 4);
  float4 w1 = *(const float4*)(w + 256 + lane * 4);
  float d = x0.x*w0.x + x0.y*w0.y + x0.z*w0.z + x0.w*w0.w
          + x1.x*w1.x + x1.y*w1.y + x1.z*w1.z + x1.w*w1.w;
#pragma unroll
  for (int off = 32; off; off >>= 1) d += __shfl_xor(d, off);
  if (lane == 0) *dst = d;
}

// generic f32 GEMM: C[M][Nn] = A[M][K] * B[K][Nn], 64x64 tile, 4x4 micro, BK=32
// batched via blockIdx.z with strides.
__global__ __launch_bounds__(256) void gemm64(
    const float* __restrict__ Abase, const float* __restrict__ Bbase,
    float* __restrict__ Cbase, int M, int Nn, int K,
    long sA, long sB, long sC)
{
  const float* A  = Abase + (long)blockIdx.z * sA;
  const float* Bm = Bbase + (long)blockIdx.z * sB;
  float* C        = Cbase + (long)blockIdx.z * sC;
  int m0 = blockIdx.x * 64, n0 = blockIdx.y * 64;
  __shared__ float a_s[32][68];
  __shared__ float b_s[32][68];
  int tid = threadIdx.x;
  int tx = tid & 15, ty = tid >> 4;
  float acc[4][4] = {};
  for (int k0 = 0; k0 < K; k0 += 32) {
#pragma unroll
    for (int l = 0; l < 2; ++l) {
      int f = tid + l * 256;
      int r = f >> 3, c = (f & 7) * 4;          // 64 rows x 8 float4 cols
      float4 v = *(const float4*)(A + (long)(m0 + r) * K + k0 + c);
      a_s[c][r] = v.x; a_s[c+1][r] = v.y; a_s[c+2][r] = v.z; a_s[c+3][r] = v.w;
    }
#pragma unroll
    for (int l = 0; l < 2; ++l) {
      int f = tid + l * 256;
      int r = f >> 4, c = (f & 15) * 4;         // 32 rows x 16 float4 cols
      *(float4*)&b_s[r][c] = *(const float4*)(Bm + (long)(k0 + r) * Nn + n0 + c);
    }
    __syncthreads();
#pragma unroll
    for (int kk = 0; kk < 32; ++kk) {
      float af[4], bf[4];
      *(float4*)af = *(const float4*)&a_s[kk][ty * 4];
      *(float4*)bf = *(const float4*)&b_s[kk][tx * 4];
#pragma unroll
      for (int i = 0; i < 4; ++i)
#pragma unroll
        for (int j = 0; j < 4; ++j) acc[i][j] = fmaf(af[i], bf[j], acc[i][j]);
    }
    __syncthreads();
  }
#pragma unroll
  for (int i = 0; i < 4; ++i) {
    float4 v = make_float4(acc[i][0], acc[i][1], acc[i][2], acc[i][3]);
    *(float4*)(C + (long)(m0 + ty * 4 + i) * Nn + n0 + tx * 4) = v;
  }
}

// fused: sim = inputs[b, t0:t0+64, :] @ aM[b]^T  (+lin_a +lin_b +bias, tanh,
// masked softmax over n) -> attn[b, t0:t0+64, :]
__global__ __launch_bounds__(256) void sim_softmax(
    const float* __restrict__ inputs, const float* __restrict__ aM,
    const float* __restrict__ lin_a, const float* __restrict__ lin_b,
    const int* __restrict__ mask, const float* __restrict__ bias,
    float* __restrict__ attn)
{
  __shared__ float in_s[32][68];
  __shared__ float am_s[32][132];
  __shared__ float S_s[64][128];
  int b = blockIdx.y;
  int t0 = blockIdx.x * 64;
  int tid = threadIdx.x;
  int tx = tid & 15, ty = tid >> 4;
  float acc[4][8] = {};
  const float* Abase = inputs + ((long)b * Tsz + t0) * Vsz;
  const float* Mbase = aM + (long)b * Nsz * Vsz;
  for (int k0 = 0; k0 < Vsz; k0 += 32) {
#pragma unroll
    for (int l = 0; l < 2; ++l) {        // inputs tile 64x32
      int f = tid + l * 256;
      int r = f >> 3, c = (f & 7) * 4;
      float4 v = *(const float4*)(Abase + (long)r * Vsz + k0 + c);
      in_s[c][r] = v.x; in_s[c+1][r] = v.y; in_s[c+2][r] = v.z; in_s[c+3][r] = v.w;
    }
#pragma unroll
    for (int l = 0; l < 4; ++l) {        // aM tile 128x32
      int f = tid + l * 256;
      int r = f >> 3, c = (f & 7) * 4;
      float4 v = *(const float4*)(Mbase + (long)r * Vsz + k0 + c);
      am_s[c][r] = v.x; am_s[c+1][r] = v.y; am_s[c+2][r] = v.z; am_s[c+3][r] = v.w;
    }
    __syncthreads();
#pragma unroll
    for (int kk = 0; kk < 32; ++kk) {
      float af[4], bf[8];
      *(float4*)af       = *(const float4*)&in_s[kk][ty * 4];
      *(float4*)bf       = *(const float4*)&am_s[kk][tx * 8];
      *(float4*)(bf + 4) = *(const float4*)&am_s[kk][tx * 8 + 4];
#pragma unroll
      for (int i = 0; i < 4; ++i)
#pragma unroll
        for (int j = 0; j < 8; ++j) acc[i][j] = fmaf(af[i], bf[j], acc[i][j]);
    }
    __syncthreads();
  }
#pragma unroll
  for (int i = 0; i < 4; ++i) {
    *(float4*)&S_s[ty * 4 + i][tx * 8]     = *(float4*)&acc[i][0];
    *(float4*)&S_s[ty * 4 + i][tx * 8 + 4] = *(float4*)&acc[i][4];
  }
  __syncthreads();

  int wave = tid >> 6, lane = tid & 63;
  float la0 = lin_a[b * Nsz + lane];
  float la1 = lin_a[b * Nsz + 64 + lane];
  int   m0  = mask[b * Nsz + lane];
  int   m1  = mask[b * Nsz + 64 + lane];
  float bs  = bias[0];
  for (int r = 0; r < 16; ++r) {
    int tl = wave * 16 + r;
    float lb = lin_b[b * Tsz + t0 + tl] + bs;
    float s0 = S_s[tl][lane] + la0 + lb;
    float s1 = S_s[tl][64 + lane] + la1 + lb;
    s0 = fast_tanh(s0); s1 = fast_tanh(s1);
    float v0 = m0 ? s0 : -1e30f;
    float v1 = m1 ? s1 : -1e30f;
    float mx = fmaxf(v0, v1);
#pragma unroll
    for (int off = 32; off; off >>= 1) mx = fmaxf(mx, __shfl_xor(mx, off));
    float e0 = m0 ? __expf(v0 - mx) : 0.f;
    float e1 = m1 ? __expf(v1 - mx) : 0.f;
    float sm = e0 + e1;
#pragma unroll
    for (int off = 32; off; off >>= 1) sm += __shfl_xor(sm, off);
    float inv = 1.f / sm;
    long base = ((long)b * Tsz + t0 + tl) * Nsz;
    attn[base + lane]      = e0 * inv;
    attn[base + 64 + lane] = e1 * inv;
  }
}

extern "C" void kernel_launch(void* const* d_in, const int* in_sizes, int n_in,
                              void* d_out, int out_size, void* d_ws, size_t ws_size,
                              hipStream_t stream) {
  const float* inputs = (const float*)d_in[0];
  const float* AO     = (const float*)d_in[1];
  const int*   mask   = (const int*)d_in[2];
  const float* W      = (const float*)d_in[3];
  const float* a_w    = (const float*)d_in[4];
  const float* b_w    = (const float*)d_in[5];
  const float* bias   = (const float*)d_in[6];
  float* out = (float*)d_out;
  float* ws  = (float*)d_ws;

  float* aM    = ws;                    // 128*128*512 = 8,388,608 f32
  float* lin_a = ws + 8388608;          // 16384
  float* lin_b = lin_a + 16384;         // 32768
  float* attn  = lin_b + 32768;         // 128*256*128 = 4,194,304
  // total ws use: 50,528,256 bytes

  // lin_a (16384 rows) + lin_b (32768 rows), one wave per row
  lin_kernel<<<(16384 + 32768) / 4, 256, 0, stream>>>(AO, inputs, a_w, b_w, lin_a, lin_b);
  // aM = AO(16384x512) @ W(512x512)
  gemm64<<<dim3(256, 8, 1), 256, 0, stream>>>(AO, W, aM, 16384, 512, 512, 0, 0, 0);
  // sim + tanh + masked softmax -> attn
  sim_softmax<<<dim3(Tsz / 64, Bsz), 256, 0, stream>>>(inputs, aM, lin_a, lin_b, mask, bias, attn);
  // context = attn(256x128) @ AO(128x512), batched over B
  gemm64<<<dim3(4, 8, Bsz), 256, 0, stream>>>(attn, AO, out, Tsz, Asz, Nsz,
                                              (long)Tsz * Nsz, (long)Nsz * Asz, (long)Tsz * Asz);
}

// Round 2
// 332.266 us; speedup vs baseline: 1.2568x; 1.2568x over previous
//
#include <hip/hip_runtime.h>

#define Bsz 128
#define Tsz 256
#define Nsz 128
#define Asz 512
#define Vsz 512
#define PAD 40

typedef __attribute__((ext_vector_type(8))) short bh8;
typedef __attribute__((ext_vector_type(4))) float f32x4;

__device__ __forceinline__ unsigned short f2bf(float x) {
  unsigned int u = __float_as_uint(x);
  return (unsigned short)((u + 0x7fffu + ((u >> 16) & 1u)) >> 16);
}
__device__ __forceinline__ float bf2f(unsigned short h) {
  return __uint_as_float(((unsigned int)h) << 16);
}

__device__ __forceinline__ float fast_tanh(float x) {
  float ax = fabsf(x);
  float e = __expf(-2.f * ax);
  float t = (1.f - e) / (1.f + e);
  return copysignf(t, x);
}

// one wave per row: dot(row, w) -> dst[row]
__global__ __launch_bounds__(256) void lin_kernel(
    const float* __restrict__ AO, const float* __restrict__ inputs,
    const float* __restrict__ a_w, const float* __restrict__ b_w,
    float* __restrict__ lin_a, float* __restrict__ lin_b)
{
  int gw = (blockIdx.x * 256 + threadIdx.x) >> 6;
  int lane = threadIdx.x & 63;
  const float* src; const float* w; float* dst;
  if (gw < Bsz * Nsz) {
    src = AO + (long)gw * Asz; w = a_w; dst = lin_a + gw;
  } else {
    int r = gw - Bsz * Nsz;
    src = inputs + (long)r * Vsz; w = b_w; dst = lin_b + r;
  }
  float4 x0 = *(const float4*)(src + lane * 4);
  float4 x1 = *(const float4*)(src + 256 + lane * 4);
  float4 w0 = *(const float4*)(w + lane * 4);
  float4 w1 = *(const float4*)(w + 256 + lane * 4);
  float d = x0.x*w0.x + x0.y*w0.y + x0.z*w0.z + x0.w*w0.w
          + x1.x*w1.x + x1.y*w1.y + x1.z*w1.z + x1.w*w1.w;
#pragma unroll
  for (int off = 32; off; off >>= 1) d += __shfl_xor(d, off);
  if (lane == 0) *dst = d;
}

// MFMA GEMM: C[M][N] = A[M][K] * B[K][N]; 128x128 tile, 4 waves (2x2), BK=32.
// SPLIT=1: both operands split hi/lo bf16, 3-term MFMA (near-f32 accuracy).
// SPLIT=0: plain bf16. B is staged transposed ([n][k]) from row-major [k][n].
template<int SPLIT>
__global__ __launch_bounds__(256) void gemm_nn(
    const float* __restrict__ Ab, const float* __restrict__ Bb,
    float* __restrict__ Cb, int lda, int ldb, int ldc, int K,
    long sA, long sB, long sC)
{
  const float* A = Ab + (long)blockIdx.z * sA;
  const float* Bm = Bb + (long)blockIdx.z * sB;
  float* C = Cb + (long)blockIdx.z * sC;
  int m0 = blockIdx.x * 128, n0 = blockIdx.y * 128;

  __shared__ unsigned short a_hi[128][PAD];
  __shared__ unsigned short b_hi[128][PAD];
  __shared__ unsigned short a_lo[SPLIT ? 128 : 1][PAD];
  __shared__ unsigned short b_lo[SPLIT ? 128 : 1][PAD];

  int tid = threadIdx.x;
  int wave = tid >> 6, lane = tid & 63;
  int wr = wave >> 1, wc = wave & 1;
  int lr = lane & 15, kg = lane >> 4;

  f32x4 acc[4][4] = {};

  for (int k0 = 0; k0 < K; k0 += 32) {
    // A tile 128x32, direct
#pragma unroll
    for (int l = 0; l < 4; ++l) {
      int f = tid + l * 256;
      int r = f >> 3, c = (f & 7) * 4;
      float4 v = *(const float4*)(A + (long)(m0 + r) * lda + k0 + c);
      float vv[4] = {v.x, v.y, v.z, v.w};
      ushort4 h, lo;
      unsigned short* hp = (unsigned short*)&h;
      unsigned short* lp = (unsigned short*)&lo;
#pragma unroll
      for (int j = 0; j < 4; ++j) {
        hp[j] = f2bf(vv[j]);
        if (SPLIT) lp[j] = f2bf(vv[j] - bf2f(hp[j]));
      }
      *(ushort4*)&a_hi[r][c] = h;
      if (SPLIT) *(ushort4*)&a_lo[r][c] = lo;
    }
    // B tile 32x128, transpose-stage to [n][k]
#pragma unroll
    for (int l = 0; l < 4; ++l) {
      int f = tid + l * 256;
      int r = f >> 5, c = (f & 31) * 4;
      float4 v = *(const float4*)(Bm + (long)(k0 + r) * ldb + n0 + c);
      float vv[4] = {v.x, v.y, v.z, v.w};
#pragma unroll
      for (int j = 0; j < 4; ++j) {
        unsigned short hh = f2bf(vv[j]);
        b_hi[c + j][r] = hh;
        if (SPLIT) b_lo[c + j][r] = f2bf(vv[j] - bf2f(hh));
      }
    }
    __syncthreads();

    bh8 ah[4], bh_[4], al[4], bl[4];
#pragma unroll
    for (int m = 0; m < 4; ++m) {
      ah[m] = *(const bh8*)&a_hi[wr * 64 + m * 16 + lr][kg * 8];
      if (SPLIT) al[m] = *(const bh8*)&a_lo[wr * 64 + m * 16 + lr][kg * 8];
    }
#pragma unroll
    for (int n = 0; n < 4; ++n) {
      bh_[n] = *(const bh8*)&b_hi[wc * 64 + n * 16 + lr][kg * 8];
      if (SPLIT) bl[n] = *(const bh8*)&b_lo[wc * 64 + n * 16 + lr][kg * 8];
    }
#pragma unroll
    for (int m = 0; m < 4; ++m)
#pragma unroll
      for (int n = 0; n < 4; ++n) {
        acc[m][n] = __builtin_amdgcn_mfma_f32_16x16x32_bf16(ah[m], bh_[n], acc[m][n], 0, 0, 0);
        if (SPLIT) {
          acc[m][n] = __builtin_amdgcn_mfma_f32_16x16x32_bf16(ah[m], bl[n], acc[m][n], 0, 0, 0);
          acc[m][n] = __builtin_amdgcn_mfma_f32_16x16x32_bf16(al[m], bh_[n], acc[m][n], 0, 0, 0);
        }
      }
    __syncthreads();
  }

#pragma unroll
  for (int m = 0; m < 4; ++m)
#pragma unroll
    for (int n = 0; n < 4; ++n)
#pragma unroll
      for (int j = 0; j < 4; ++j)
        C[(long)(m0 + wr * 64 + m * 16 + kg * 4 + j) * ldc + n0 + wc * 64 + n * 16 + lr] = acc[m][n][j];
}

// fused: sim tile (128 t-rows x all 128 n) via 3-term split MFMA, then
// +lin_a+lin_b+bias, tanh, masked softmax over n -> attn (f32)
__global__ __launch_bounds__(256) void sim_fused(
    const float* __restrict__ inputs, const float* __restrict__ aM,
    const float* __restrict__ lin_a, const float* __restrict__ lin_b,
    const int* __restrict__ mask, const float* __restrict__ bias,
    float* __restrict__ attn)
{
  __shared__ union SU {
    struct { unsigned short a_hi[128][PAD], a_lo[128][PAD], b_hi[128][PAD], b_lo[128][PAD]; } st;
    float S[128][132];
  } u;

  int b = blockIdx.y;
  int t0 = blockIdx.x * 128;
  int tid = threadIdx.x;
  int wave = tid >> 6, lane = tid & 63;
  int wr = wave >> 1, wc = wave & 1;
  int lr = lane & 15, kg = lane >> 4;

  const float* Ap = inputs + ((long)b * Tsz + t0) * Vsz;
  const float* Bp = aM + (long)b * Nsz * Vsz;

  f32x4 acc[4][4] = {};

  for (int k0 = 0; k0 < Vsz; k0 += 32) {
#pragma unroll
    for (int l = 0; l < 4; ++l) {   // inputs tile 128x32 (direct)
      int f = tid + l * 256;
      int r = f >> 3, c = (f & 7) * 4;
      float4 v = *(const float4*)(Ap + (long)r * Vsz + k0 + c);
      float vv[4] = {v.x, v.y, v.z, v.w};
      ushort4 h, lo;
      unsigned short* hp = (unsigned short*)&h;
      unsigned short* lp = (unsigned short*)&lo;
#pragma unroll
      for (int j = 0; j < 4; ++j) {
        hp[j] = f2bf(vv[j]);
        lp[j] = f2bf(vv[j] - bf2f(hp[j]));
      }
      *(ushort4*)&u.st.a_hi[r][c] = h;
      *(ushort4*)&u.st.a_lo[r][c] = lo;
    }
#pragma unroll
    for (int l = 0; l < 4; ++l) {   // aM tile 128x32 (direct, already [n][v])
      int f = tid + l * 256;
      int r = f >> 3, c = (f & 7) * 4;
      float4 v = *(const float4*)(Bp + (long)r * Vsz + k0 + c);
      float vv[4] = {v.x, v.y, v.z, v.w};
      ushort4 h, lo;
      unsigned short* hp = (unsigned short*)&h;
      unsigned short* lp = (unsigned short*)&lo;
#pragma unroll
      for (int j = 0; j < 4; ++j) {
        hp[j] = f2bf(vv[j]);
        lp[j] = f2bf(vv[j] - bf2f(hp[j]));
      }
      *(ushort4*)&u.st.b_hi[r][c] = h;
      *(ushort4*)&u.st.b_lo[r][c] = lo;
    }
    __syncthreads();

    bh8 ah[4], bh_[4], al[4], bl[4];
#pragma unroll
    for (int m = 0; m < 4; ++m) {
      ah[m] = *(const bh8*)&u.st.a_hi[wr * 64 + m * 16 + lr][kg * 8];
      al[m] = *(const bh8*)&u.st.a_lo[wr * 64 + m * 16 + lr][kg * 8];
    }
#pragma unroll
    for (int n = 0; n < 4; ++n) {
      bh_[n] = *(const bh8*)&u.st.b_hi[wc * 64 + n * 16 + lr][kg * 8];
      bl[n] = *(const bh8*)&u.st.b_lo[wc * 64 + n * 16 + lr][kg * 8];
    }
#pragma unroll
    for (int m = 0; m < 4; ++m)
#pragma unroll
      for (int n = 0; n < 4; ++n) {
        acc[m][n] = __builtin_amdgcn_mfma_f32_16x16x32_bf16(ah[m], bh_[n], acc[m][n], 0, 0, 0);
        acc[m][n] = __builtin_amdgcn_mfma_f32_16x16x32_bf16(ah[m], bl[n], acc[m][n], 0, 0, 0);
        acc[m][n] = __builtin_amdgcn_mfma_f32_16x16x32_bf16(al[m], bh_[n], acc[m][n], 0, 0, 0);
      }
    __syncthreads();
  }

  // scores -> LDS (aliases staging buffers; all compute reads are done)
#pragma unroll
  for (int m = 0; m < 4; ++m)
#pragma unroll
    for (int n = 0; n < 4; ++n)
#pragma unroll
      for (int j = 0; j < 4; ++j)
        u.S[wr * 64 + m * 16 + kg * 4 + j][wc * 64 + n * 16 + lr] = acc[m][n][j];
  __syncthreads();

  // masked softmax over n (128), 32 rows per wave
  float la0 = lin_a[b * Nsz + lane];
  float la1 = lin_a[b * Nsz + 64 + lane];
  int   mk0 = mask[b * Nsz + lane];
  int   mk1 = mask[b * Nsz + 64 + lane];
  float bs  = bias[0];
  for (int r8 = 0; r8 < 32; ++r8) {
    int r = wave * 32 + r8;
    int t = t0 + r;
    float lb = lin_b[b * Tsz + t] + bs;
    float s0 = u.S[r][lane] + la0 + lb;
    float s1 = u.S[r][64 + lane] + la1 + lb;
    s0 = fast_tanh(s0); s1 = fast_tanh(s1);
    float v0 = mk0 ? s0 : -1e30f;
    float v1 = mk1 ? s1 : -1e30f;
    float mx = fmaxf(v0, v1);
#pragma unroll
    for (int off = 32; off; off >>= 1) mx = fmaxf(mx, __shfl_xor(mx, off));
    float e0 = mk0 ? __expf(v0 - mx) : 0.f;
    float e1 = mk1 ? __expf(v1 - mx) : 0.f;
    float sm = e0 + e1;
#pragma unroll
    for (int off = 32; off; off >>= 1) sm += __shfl_xor(sm, off);
    float inv = 1.f / sm;
    long base = ((long)b * Tsz + t) * Nsz;
    attn[base + lane]      = e0 * inv;
    attn[base + 64 + lane] = e1 * inv;
  }
}

extern "C" void kernel_launch(void* const* d_in, const int* in_sizes, int n_in,
                              void* d_out, int out_size, void* d_ws, size_t ws_size,
                              hipStream_t stream) {
  const float* inputs = (const float*)d_in[0];
  const float* AO     = (const float*)d_in[1];
  const int*   mask   = (const int*)d_in[2];
  const float* W      = (const float*)d_in[3];
  const float* a_w    = (const float*)d_in[4];
  const float* b_w    = (const float*)d_in[5];
  const float* bias   = (const float*)d_in[6];
  float* out = (float*)d_out;
  float* ws  = (float*)d_ws;

  float* aM    = ws;                    // 8,388,608 f32
  float* lin_a = ws + 8388608;          // 16384
  float* lin_b = lin_a + 16384;         // 32768
  float* attn  = lin_b + 32768;         // 4,194,304 f32

  lin_kernel<<<(16384 + 32768) / 4, 256, 0, stream>>>(AO, inputs, a_w, b_w, lin_a, lin_b);
  // aM = AO(16384x512) @ W(512x512), split-bf16 3-term
  gemm_nn<1><<<dim3(128, 4, 1), 256, 0, stream>>>(AO, W, aM, Asz, Vsz, Vsz, Asz, 0, 0, 0);
  // sim + tanh + masked softmax -> attn (f32)
  sim_fused<<<dim3(Tsz / 128, Bsz), 256, 0, stream>>>(inputs, aM, lin_a, lin_b, mask, bias, attn);
  // context = attn(256x128) @ AO(128x512), plain bf16, batched over B
  gemm_nn<0><<<dim3(2, 4, Bsz), 256, 0, stream>>>(attn, AO, out, Nsz, Asz, Asz, Nsz,
                                                  (long)Tsz * Nsz, (long)Nsz * Asz, (long)Tsz * Asz);
}

// Round 3
// 258.367 us; speedup vs baseline: 1.6162x; 1.2860x over previous
//
#include <hip/hip_runtime.h>

#define Bsz 128
#define Tsz 256
#define Nsz 128
#define Asz 512
#define Vsz 512
#define PAD 40
#define LIN_BLOCKS 12288

typedef __attribute__((ext_vector_type(8))) short bh8;
typedef __attribute__((ext_vector_type(8))) unsigned short us8;
typedef __attribute__((ext_vector_type(4))) float f32x4;

__device__ __forceinline__ unsigned short f2bf(float x) {
  unsigned int u = __float_as_uint(x);
  return (unsigned short)((u + 0x7fffu + ((u >> 16) & 1u)) >> 16);
}
__device__ __forceinline__ float bf2f(unsigned short h) {
  return __uint_as_float(((unsigned int)h) << 16);
}
__device__ __forceinline__ float fast_tanh(float x) {
  float ax = fabsf(x);
  float e = __expf(-2.f * ax);
  float t = (1.f - e) / (1.f + e);
  return copysignf(t, x);
}

// lin_a/lin_b (one wave per row) + W^T -> hi/lo bf16 (converted ONCE)
__global__ __launch_bounds__(256) void prep(
    const float* __restrict__ AO, const float* __restrict__ inputs,
    const float* __restrict__ W, const float* __restrict__ a_w,
    const float* __restrict__ b_w, float* __restrict__ lin_a,
    float* __restrict__ lin_b, unsigned short* __restrict__ WT_hi,
    unsigned short* __restrict__ WT_lo)
{
  __shared__ float t[64][65];
  int tid = threadIdx.x;
  if (blockIdx.x < LIN_BLOCKS) {
    int gw = (blockIdx.x * 256 + tid) >> 6;
    int lane = tid & 63;
    const float* src; const float* w; float* dst;
    if (gw < Bsz * Nsz) { src = AO + (long)gw * Asz; w = a_w; dst = lin_a + gw; }
    else { int r = gw - Bsz * Nsz; src = inputs + (long)r * Vsz; w = b_w; dst = lin_b + r; }
    float4 x0 = *(const float4*)(src + lane * 4);
    float4 x1 = *(const float4*)(src + 256 + lane * 4);
    float4 w0 = *(const float4*)(w + lane * 4);
    float4 w1 = *(const float4*)(w + 256 + lane * 4);
    float d = x0.x*w0.x + x0.y*w0.y + x0.z*w0.z + x0.w*w0.w
            + x1.x*w1.x + x1.y*w1.y + x1.z*w1.z + x1.w*w1.w;
#pragma unroll
    for (int off = 32; off; off >>= 1) d += __shfl_xor(d, off);
    if (lane == 0) *dst = d;
  } else {
    int bb = blockIdx.x - LIN_BLOCKS;
    int a0 = (bb & 7) * 64, v0 = (bb >> 3) * 64;
#pragma unroll
    for (int l = 0; l < 4; ++l) {
      int idx = tid + l * 256;
      int r = idx >> 4, c = (idx & 15) * 4;
      float4 v = *(const float4*)(W + (long)(a0 + r) * Vsz + v0 + c);
      t[r][c] = v.x; t[r][c+1] = v.y; t[r][c+2] = v.z; t[r][c+3] = v.w;
    }
    __syncthreads();
#pragma unroll
    for (int l = 0; l < 4; ++l) {
      int idx = tid + l * 256;
      int r = idx >> 4, c = (idx & 15) * 4;   // r = v-local, c = a-local
      ushort4 h, lo;
      unsigned short* hp = (unsigned short*)&h;
      unsigned short* lp = (unsigned short*)&lo;
#pragma unroll
      for (int j = 0; j < 4; ++j) {
        float x = t[c + j][r];
        hp[j] = f2bf(x);
        lp[j] = f2bf(x - bf2f(hp[j]));
      }
      *(ushort4*)&WT_hi[(long)(v0 + r) * Asz + a0 + c] = h;
      *(ushort4*)&WT_lo[(long)(v0 + r) * Asz + a0 + c] = lo;
    }
  }
}

// aM = AO @ W (split-bf16 3-term). A converted in-kernel; B = pre-converted WT
// (pure vector copies). Output packed u32 = hi | lo<<16.
__global__ __launch_bounds__(256) void gemm_aM(
    const float* __restrict__ AO, const unsigned short* __restrict__ WT_hi,
    const unsigned short* __restrict__ WT_lo, unsigned int* __restrict__ aMp)
{
  int m0 = blockIdx.x * 128, n0 = blockIdx.y * 128;
  __shared__ unsigned short a_hi[128][PAD], a_lo[128][PAD];
  __shared__ unsigned short b_hi[128][PAD], b_lo[128][PAD];
  int tid = threadIdx.x;
  int wave = tid >> 6, lane = tid & 63;
  int wr = wave >> 1, wc = wave & 1;
  int lr = lane & 15, kg = lane >> 4;
  f32x4 acc[4][4] = {};
  for (int k0 = 0; k0 < Asz; k0 += 32) {
#pragma unroll
    for (int l = 0; l < 4; ++l) {
      int idx = tid + l * 256;
      int r = idx >> 3, c = (idx & 7) * 4;
      float4 v = *(const float4*)(AO + (long)(m0 + r) * Asz + k0 + c);
      float vv[4] = {v.x, v.y, v.z, v.w};
      ushort4 h, lo;
      unsigned short* hp = (unsigned short*)&h;
      unsigned short* lp = (unsigned short*)&lo;
#pragma unroll
      for (int j = 0; j < 4; ++j) {
        hp[j] = f2bf(vv[j]);
        lp[j] = f2bf(vv[j] - bf2f(hp[j]));
      }
      *(ushort4*)&a_hi[r][c] = h;
      *(ushort4*)&a_lo[r][c] = lo;
    }
#pragma unroll
    for (int l = 0; l < 2; ++l) {
      int idx = tid + l * 256;
      int r = idx >> 2, c = (idx & 3) * 8;
      *(us8*)&b_hi[r][c] = *(const us8*)&WT_hi[(long)(n0 + r) * Asz + k0 + c];
      *(us8*)&b_lo[r][c] = *(const us8*)&WT_lo[(long)(n0 + r) * Asz + k0 + c];
    }
    __syncthreads();
    bh8 ah[4], bh_[4], al[4], bl[4];
#pragma unroll
    for (int m = 0; m < 4; ++m) {
      ah[m] = *(const bh8*)&a_hi[wr * 64 + m * 16 + lr][kg * 8];
      al[m] = *(const bh8*)&a_lo[wr * 64 + m * 16 + lr][kg * 8];
    }
#pragma unroll
    for (int n = 0; n < 4; ++n) {
      bh_[n] = *(const bh8*)&b_hi[wc * 64 + n * 16 + lr][kg * 8];
      bl[n]  = *(const bh8*)&b_lo[wc * 64 + n * 16 + lr][kg * 8];
    }
#pragma unroll
    for (int m = 0; m < 4; ++m)
#pragma unroll
      for (int n = 0; n < 4; ++n) {
        acc[m][n] = __builtin_amdgcn_mfma_f32_16x16x32_bf16(ah[m], bh_[n], acc[m][n], 0, 0, 0);
        acc[m][n] = __builtin_amdgcn_mfma_f32_16x16x32_bf16(ah[m], bl[n], acc[m][n], 0, 0, 0);
        acc[m][n] = __builtin_amdgcn_mfma_f32_16x16x32_bf16(al[m], bh_[n], acc[m][n], 0, 0, 0);
      }
    __syncthreads();
  }
#pragma unroll
  for (int m = 0; m < 4; ++m)
#pragma unroll
    for (int n = 0; n < 4; ++n)
#pragma unroll
      for (int j = 0; j < 4; ++j) {
        float x = acc[m][n][j];
        unsigned short h = f2bf(x);
        unsigned short l2 = f2bf(x - bf2f(h));
        aMp[(long)(m0 + wr * 64 + m * 16 + kg * 4 + j) * Vsz + n0 + wc * 64 + n * 16 + lr]
          = (unsigned int)h | ((unsigned int)l2 << 16);
      }
}

// sim = inputs @ aM^T (3-term) + lin + bias -> tanh -> masked softmax -> attn bf16
__global__ __launch_bounds__(512) void sim_fused(
    const float* __restrict__ inputs, const unsigned int* __restrict__ aMp,
    const float* __restrict__ lin_a, const float* __restrict__ lin_b,
    const int* __restrict__ mask, const float* __restrict__ bias,
    unsigned short* __restrict__ attn_bf)
{
  __shared__ union SU {
    struct { unsigned short a_hi[128][PAD], a_lo[128][PAD], b_hi[128][PAD], b_lo[128][PAD]; } st;
    float S[128][132];
  } u;
  int b = blockIdx.y;
  int t0 = blockIdx.x * 128;
  int tid = threadIdx.x;
  int wave = tid >> 6, lane = tid & 63;
  int wr = wave >> 1, wc = wave & 1;     // wr 0..3 (32 rows each), wc 0..1 (64 cols)
  int lr = lane & 15, kg = lane >> 4;
  const float* Ap = inputs + ((long)b * Tsz + t0) * Vsz;
  const unsigned int* Bp = aMp + (long)b * Nsz * Vsz;
  f32x4 acc[2][4] = {};
  for (int k0 = 0; k0 < Vsz; k0 += 32) {
#pragma unroll
    for (int l = 0; l < 2; ++l) {
      int idx = tid + l * 512;
      int r = idx >> 3, c = (idx & 7) * 4;
      float4 v = *(const float4*)(Ap + (long)r * Vsz + k0 + c);
      float vv[4] = {v.x, v.y, v.z, v.w};
      ushort4 h, lo;
      unsigned short* hp = (unsigned short*)&h;
      unsigned short* lp = (unsigned short*)&lo;
#pragma unroll
      for (int j = 0; j < 4; ++j) {
        hp[j] = f2bf(vv[j]);
        lp[j] = f2bf(vv[j] - bf2f(hp[j]));
      }
      *(ushort4*)&u.st.a_hi[r][c] = h;
      *(ushort4*)&u.st.a_lo[r][c] = lo;
    }
#pragma unroll
    for (int l = 0; l < 2; ++l) {
      int idx = tid + l * 512;
      int r = idx >> 3, c = (idx & 7) * 4;
      uint4 v = *(const uint4*)(Bp + (long)r * Vsz + k0 + c);
      unsigned int vv[4] = {v.x, v.y, v.z, v.w};
      ushort4 h, lo;
      unsigned short* hp = (unsigned short*)&h;
      unsigned short* lp = (unsigned short*)&lo;
#pragma unroll
      for (int j = 0; j < 4; ++j) {
        hp[j] = (unsigned short)(vv[j] & 0xffffu);
        lp[j] = (unsigned short)(vv[j] >> 16);
      }
      *(ushort4*)&u.st.b_hi[r][c] = h;
      *(ushort4*)&u.st.b_lo[r][c] = lo;
    }
    __syncthreads();
    bh8 ah[2], al[2], bh_[4], bl[4];
#pragma unroll
    for (int m = 0; m < 2; ++m) {
      ah[m] = *(const bh8*)&u.st.a_hi[wr * 32 + m * 16 + lr][kg * 8];
      al[m] = *(const bh8*)&u.st.a_lo[wr * 32 + m * 16 + lr][kg * 8];
    }
#pragma unroll
    for (int n = 0; n < 4; ++n) {
      bh_[n] = *(const bh8*)&u.st.b_hi[wc * 64 + n * 16 + lr][kg * 8];
      bl[n]  = *(const bh8*)&u.st.b_lo[wc * 64 + n * 16 + lr][kg * 8];
    }
#pragma unroll
    for (int m = 0; m < 2; ++m)
#pragma unroll
      for (int n = 0; n < 4; ++n) {
        acc[m][n] = __builtin_amdgcn_mfma_f32_16x16x32_bf16(ah[m], bh_[n], acc[m][n], 0, 0, 0);
        acc[m][n] = __builtin_amdgcn_mfma_f32_16x16x32_bf16(ah[m], bl[n], acc[m][n], 0, 0, 0);
        acc[m][n] = __builtin_amdgcn_mfma_f32_16x16x32_bf16(al[m], bh_[n], acc[m][n], 0, 0, 0);
      }
    __syncthreads();
  }
#pragma unroll
  for (int m = 0; m < 2; ++m)
#pragma unroll
    for (int n = 0; n < 4; ++n)
#pragma unroll
      for (int j = 0; j < 4; ++j)
        u.S[wr * 32 + m * 16 + kg * 4 + j][wc * 64 + n * 16 + lr] = acc[m][n][j];
  __syncthreads();

  float la0 = lin_a[b * Nsz + lane];
  float la1 = lin_a[b * Nsz + 64 + lane];
  int   mk0 = mask[b * Nsz + lane];
  int   mk1 = mask[b * Nsz + 64 + lane];
  float bs  = bias[0];
  for (int r8 = 0; r8 < 16; ++r8) {
    int r = wave * 16 + r8;
    int tI = t0 + r;
    float lb = lin_b[b * Tsz + tI] + bs;
    float s0 = u.S[r][lane] + la0 + lb;
    float s1 = u.S[r][64 + lane] + la1 + lb;
    s0 = fast_tanh(s0); s1 = fast_tanh(s1);
    float v0 = mk0 ? s0 : -1e30f;
    float v1 = mk1 ? s1 : -1e30f;
    float mx = fmaxf(v0, v1);
#pragma unroll
    for (int off = 32; off; off >>= 1) mx = fmaxf(mx, __shfl_xor(mx, off));
    float e0 = mk0 ? __expf(v0 - mx) : 0.f;
    float e1 = mk1 ? __expf(v1 - mx) : 0.f;
    float sm = e0 + e1;
#pragma unroll
    for (int off = 32; off; off >>= 1) sm += __shfl_xor(sm, off);
    float inv = 1.f / sm;
    long base = ((long)b * Tsz + tI) * Nsz;
    attn_bf[base + lane]      = f2bf(e0 * inv);
    attn_bf[base + 64 + lane] = f2bf(e1 * inv);
  }
}

// AO[b][n][a] f32 -> AOt[b][a][n] bf16 (XOR-swizzled LDS transpose)
__global__ __launch_bounds__(256) void ao_transpose(
    const float* __restrict__ AO, unsigned short* __restrict__ AOt)
{
  __shared__ unsigned short t[128][128];
  int b = blockIdx.x >> 2;
  int a0 = (blockIdx.x & 3) * 128;
  int tid = threadIdx.x;
#pragma unroll
  for (int l = 0; l < 16; ++l) {
    int idx = tid + l * 256;
    int r = idx >> 5, c = (idx & 31) * 4;      // r = n, c = a-local
    float4 v = *(const float4*)(AO + ((long)b * Nsz + r) * Asz + a0 + c);
    ushort4 h;
    unsigned short* hp = (unsigned short*)&h;
    hp[0] = f2bf(v.x); hp[1] = f2bf(v.y); hp[2] = f2bf(v.z); hp[3] = f2bf(v.w);
    int key = ((r >> 3) & 7) << 2;
    *(ushort4*)&t[r][c ^ key] = h;
  }
  __syncthreads();
#pragma unroll
  for (int l = 0; l < 8; ++l) {
    int idx = tid + l * 256;
    int ra = idx >> 4, cc = idx & 15;          // ra = a-local, cc = n-chunk
    int key = (cc & 7) << 2;
    us8 g;
#pragma unroll
    for (int j = 0; j < 8; ++j) g[j] = t[cc * 8 + j][ra ^ key];
    *(us8*)&AOt[((long)b * Asz + a0 + ra) * Nsz + cc * 8] = g;
  }
}

// context = attn(bf16) @ AO via AOt (both operands pre-layouted, pure copies)
__global__ __launch_bounds__(256) void gemm_ctx(
    const unsigned short* __restrict__ attn_bf, const unsigned short* __restrict__ AOt,
    float* __restrict__ out)
{
  int b = blockIdx.z;
  int m0 = blockIdx.x * 128, n0 = blockIdx.y * 128;
  __shared__ unsigned short a_t[128][PAD], b_t[128][PAD];
  int tid = threadIdx.x;
  int wave = tid >> 6, lane = tid & 63;
  int wr = wave >> 1, wc = wave & 1;
  int lr = lane & 15, kg = lane >> 4;
  const unsigned short* Ap = attn_bf + (long)b * Tsz * Nsz;
  const unsigned short* Bp = AOt + (long)b * Asz * Nsz;
  f32x4 acc[4][4] = {};
  for (int k0 = 0; k0 < Nsz; k0 += 32) {
#pragma unroll
    for (int l = 0; l < 2; ++l) {
      int idx = tid + l * 256;
      int r = idx >> 2, c = (idx & 3) * 8;
      *(us8*)&a_t[r][c] = *(const us8*)&Ap[(long)(m0 + r) * Nsz + k0 + c];
      *(us8*)&b_t[r][c] = *(const us8*)&Bp[(long)(n0 + r) * Nsz + k0 + c];
    }
    __syncthreads();
    bh8 af[4], bf_[4];
#pragma unroll
    for (int m = 0; m < 4; ++m) af[m] = *(const bh8*)&a_t[wr * 64 + m * 16 + lr][kg * 8];
#pragma unroll
    for (int n = 0; n < 4; ++n) bf_[n] = *(const bh8*)&b_t[wc * 64 + n * 16 + lr][kg * 8];
#pragma unroll
    for (int m = 0; m < 4; ++m)
#pragma unroll
      for (int n = 0; n < 4; ++n)
        acc[m][n] = __builtin_amdgcn_mfma_f32_16x16x32_bf16(af[m], bf_[n], acc[m][n], 0, 0, 0);
    __syncthreads();
  }
#pragma unroll
  for (int m = 0; m < 4; ++m)
#pragma unroll
    for (int n = 0; n < 4; ++n)
#pragma unroll
      for (int j = 0; j < 4; ++j)
        out[((long)b * Tsz + m0 + wr * 64 + m * 16 + kg * 4 + j) * Asz + n0 + wc * 64 + n * 16 + lr]
          = acc[m][n][j];
}

extern "C" void kernel_launch(void* const* d_in, const int* in_sizes, int n_in,
                              void* d_out, int out_size, void* d_ws, size_t ws_size,
                              hipStream_t stream) {
  const float* inputs = (const float*)d_in[0];
  const float* AO     = (const float*)d_in[1];
  const int*   mask   = (const int*)d_in[2];
  const float* W      = (const float*)d_in[3];
  const float* a_w    = (const float*)d_in[4];
  const float* b_w    = (const float*)d_in[5];
  const float* bias   = (const float*)d_in[6];
  float* out = (float*)d_out;
  char* wsb  = (char*)d_ws;

  unsigned int*   aMp     = (unsigned int*)wsb;                  // 33,554,432 B
  unsigned short* AOt     = (unsigned short*)wsb;                // overlaps aMp (after sim)
  unsigned short* WT_hi   = (unsigned short*)(wsb + 33554432);   // 524,288 B
  unsigned short* WT_lo   = (unsigned short*)(wsb + 34078720);   // 524,288 B
  float*          lin_a   = (float*)(wsb + 34603008);            // 65,536 B
  float*          lin_b   = (float*)(wsb + 34668544);            // 131,072 B
  unsigned short* attn_bf = (unsigned short*)(wsb + 34799616);   // 8,388,608 B -> ends 43.2 MB

  prep<<<LIN_BLOCKS + 64, 256, 0, stream>>>(AO, inputs, W, a_w, b_w, lin_a, lin_b, WT_hi, WT_lo);
  gemm_aM<<<dim3(128, 4), 256, 0, stream>>>(AO, WT_hi, WT_lo, aMp);
  sim_fused<<<dim3(2, 128), 512, 0, stream>>>(inputs, aMp, lin_a, lin_b, mask, bias, attn_bf);
  ao_transpose<<<512, 256, 0, stream>>>(AO, AOt);
  gemm_ctx<<<dim3(2, 4, 128), 256, 0, stream>>>(attn_bf, AOt, out);
}